// Round 2
// baseline (1070.302 us; speedup 1.0000x reference)
//
#include <hip/hip_runtime.h>
#include <math.h>

// Problem constants
#define NPTS   16384      // 16 * 32 * 32 points
#define NE     8192       // codebook entries
#define DIM    256        // embedding dim
#define BIMG   16
#define HW     1024       // 32*32
#define ZQ_N   4194304    // 16*256*32*32
#define OFF_LOSS  4194304
#define OFF_PERP  4194305
#define OFF_IDX   4194306

// K1 tiling
#define BP     64         // points per block
#define BC     256        // codes per chunk
#define KC     32         // dims per k-chunk
#define SPLITS 2
#define CC_TOT (NE / BC)              // 32 chunks
#define CC_PER (CC_TOT / SPLITS)      // 16 per split

// f32 multiply that can NOT be contracted into an FMA by -ffp-contract=fast
// (numpy materializes zf*zf, rounding the square, before the pairwise sum).
__device__ __forceinline__ float mul_rn(float a, float b) {
    float r;
    asm("v_mul_f32 %0, %1, %2" : "=v"(r) : "v"(a), "v"(b));
    return r;
}

// ---------------------------------------------------------------------------
// K_zsq: ||z||^2 per point, bit-replicating numpy pairwise_sum(n=256):
//   pw(256) = pw(first 128) + pw(second 128)
//   pw(128) = 8 accumulators r[j] = a[j] (+= a[8i+j]), combined
//             ((r0+r1)+(r2+r3)) + ((r4+r5)+(r6+r7))
// 2 threads per point (adjacent lanes = the two 128-halves).
// ---------------------------------------------------------------------------
__global__ void k_zsq(const float* __restrict__ z, float* __restrict__ zsq) {
    int gid = blockIdx.x * 256 + threadIdx.x;   // 32768 threads
    int P = gid >> 1, half = gid & 1;
    int b = P >> 10, hw = P & 1023;
    const float* zb = z + (size_t)b * (DIM * HW) + (size_t)(half * 128) * HW + hw;
    float r[8];
    #pragma unroll
    for (int j = 0; j < 8; ++j) {
        float v = zb[(size_t)j * HW];
        r[j] = mul_rn(v, v);
    }
    #pragma unroll
    for (int i = 8; i < 128; i += 8)
        #pragma unroll
        for (int j = 0; j < 8; ++j) {
            float v = zb[(size_t)(i + j) * HW];
            r[j] += mul_rn(v, v);
        }
    float s = ((r[0] + r[1]) + (r[2] + r[3])) + ((r[4] + r[5]) + (r[6] + r[7]));
    float o = __shfl_xor(s, 1, 64);
    if (half == 0) zsq[P] = s + o;   // half0 + half1, numpy's combine order
}

// ---------------------------------------------------------------------------
// K_init: zero the histogram
// ---------------------------------------------------------------------------
__global__ void k_init(int* __restrict__ hist) {
    hist[blockIdx.x * 256 + threadIdx.x] = 0;
}

// ---------------------------------------------------------------------------
// K1: argmin_j fl(zsq_i - 2*dot_ij), dot = sequential f32 FMA chain over
// k=0..255 in ascending order (replicates BLAS/Eigen gebp accumulation).
// Note ||e||^2 is erased by the reference's f32 add (1.3e-6 << half-ulp at
// 256), so it is dropped entirely.
// block: 256 threads = 8 point-groups (ty) x 32 code-lanes (tx)
// per-thread tile: 8 points x 8 codes
// ---------------------------------------------------------------------------
__global__ __launch_bounds__(256, 2)
void k_argmin(const float* __restrict__ z, const float* __restrict__ emb,
              const float* __restrict__ zsq,
              float* __restrict__ cand_d, int* __restrict__ cand_c) {
    const int blk   = blockIdx.x;
    const int pblk  = blk & 255;       // 256 point-blocks
    const int split = blk >> 8;        // 0..SPLITS-1
    const int p0    = pblk * BP;
    const int b     = p0 >> 10;
    const int hw0   = p0 & 1023;
    const int t  = threadIdx.x;
    const int tx = t & 31;
    const int ty = t >> 5;

    __shared__ __align__(16) float z_s[BP][36];   // padded
    __shared__ __align__(16) float e_s[BC][36];

    float bd[8];
    int   bcn[8];
    #pragma unroll
    for (int i = 0; i < 8; ++i) { bd[i] = INFINITY; bcn[i] = 0x7fffffff; }

    float zsqv[8];
    #pragma unroll
    for (int i = 0; i < 8; ++i) zsqv[i] = zsq[p0 + ty * 8 + i];

    const float* zbase = z + (size_t)b * (DIM * HW) + hw0;

    for (int cc = split * CC_PER; cc < (split + 1) * CC_PER; ++cc) {
        float acc[8][8];
        #pragma unroll
        for (int i = 0; i < 8; ++i)
            #pragma unroll
            for (int j = 0; j < 8; ++j) acc[i][j] = 0.f;

        for (int kc = 0; kc < DIM / KC; ++kc) {
            __syncthreads();
            // stage z chunk: z_s[i][kk] = z[b][kc*32+kk][hw0+i]
            {
                int i   = t & 63;
                int kk0 = t >> 6;          // 0..3
                #pragma unroll
                for (int r = 0; r < 8; ++r) {
                    int kk = kk0 + r * 4;
                    z_s[i][kk] = zbase[(size_t)(kc * KC + kk) * HW + i];
                }
            }
            // stage e chunk: e_s[r][kk] = emb[cc*256+r][kc*32+kk]  (float4)
            {
                #pragma unroll
                for (int it = 0; it < 8; ++it) {
                    int q   = t + it * 256;     // 0..2047
                    int r   = q >> 3;
                    int kkq = q & 7;
                    const float4 v = *(const float4*)(emb +
                        (size_t)(cc * BC + r) * DIM + kc * KC + kkq * 4);
                    *(float4*)&e_s[r][kkq * 4] = v;
                }
            }
            __syncthreads();

            #pragma unroll
            for (int g = 0; g < 8; ++g) {       // ascending 4-dim groups
                float4 zf[8], ef[8];
                #pragma unroll
                for (int i = 0; i < 8; ++i)
                    zf[i] = *(const float4*)&z_s[ty * 8 + i][g * 4];
                #pragma unroll
                for (int j = 0; j < 8; ++j)
                    ef[j] = *(const float4*)&e_s[tx + j * 32][g * 4];
                #pragma unroll
                for (int i = 0; i < 8; ++i)
                    #pragma unroll
                    for (int j = 0; j < 8; ++j) {
                        float a = acc[i][j];
                        a = fmaf(zf[i].x, ef[j].x, a);   // k ascending,
                        a = fmaf(zf[i].y, ef[j].y, a);   // single accumulator,
                        a = fmaf(zf[i].z, ef[j].z, a);   // fused per step —
                        a = fmaf(zf[i].w, ef[j].w, a);   // matches sgemm
                        acc[i][j] = a;
                    }
            }
        }
        // fold chunk into running best. d = fl(zsq - 2*acc): the 2*acc
        // product is exact, so contracted/non-contracted forms agree.
        #pragma unroll
        for (int j = 0; j < 8; ++j) {
            int c = cc * BC + tx + j * 32;
            #pragma unroll
            for (int i = 0; i < 8; ++i) {
                float d = zsqv[i] - 2.0f * acc[i][j];
                if (d < bd[i]) { bd[i] = d; bcn[i] = c; }
                else if (d == bd[i] && c < bcn[i]) { bcn[i] = c; }
            }
        }
    }

    // reduce across the 32 code-lanes, keep lowest idx on ties
    #pragma unroll
    for (int i = 0; i < 8; ++i) {
        float d = bd[i];
        int   c = bcn[i];
        #pragma unroll
        for (int m = 16; m >= 1; m >>= 1) {
            float od = __shfl_xor(d, m, 32);
            int   oc = __shfl_xor(c, m, 32);
            if (od < d || (od == d && oc < c)) { d = od; c = oc; }
        }
        if (tx == 0) {
            int P = p0 + ty * 8 + i;
            cand_d[(size_t)split * NPTS + P] = d;
            cand_c[(size_t)split * NPTS + P] = c;
        }
    }
}

// ---------------------------------------------------------------------------
// K1b: combine the SPLITS candidates, emit final index + histogram
// ---------------------------------------------------------------------------
__global__ void k_pick(const float* __restrict__ cand_d,
                       const int* __restrict__ cand_c,
                       int* __restrict__ idx_i, int* __restrict__ hist,
                       float* __restrict__ out) {
    int P = blockIdx.x * 256 + threadIdx.x;
    float d0 = cand_d[P], d1 = cand_d[NPTS + P];
    int   c0 = cand_c[P], c1 = cand_c[NPTS + P];
    // split0 codes < split1 codes, so ties go to c0 (lower index)
    int idx = (d1 < d0) ? c1 : c0;
    idx_i[P] = idx;
    out[OFF_IDX + P] = (float)idx;
    atomicAdd(&hist[idx], 1);
}

// ---------------------------------------------------------------------------
// K2: gather z_q (NCHW) with STE rounding fl(z + fl(e - z)), loss partials
// ---------------------------------------------------------------------------
__global__ __launch_bounds__(256)
void k_gather(const float* __restrict__ z, const float* __restrict__ emb,
              const int* __restrict__ idx_i, float* __restrict__ out,
              float* __restrict__ partials) {
    int bid = blockIdx.x;          // 0..4095
    int c = bid & 255;
    int b = bid >> 8;
    int t = threadIdx.x;
    int hw = t * 4;

    size_t zoff = (size_t)(b * DIM + c) * HW + hw;
    const float4 zv = *(const float4*)(z + zoff);
    const int4  iv = *(const int4*)(idx_i + b * HW + hw);

    float e0 = emb[(size_t)iv.x * DIM + c];
    float e1 = emb[(size_t)iv.y * DIM + c];
    float e2 = emb[(size_t)iv.z * DIM + c];
    float e3 = emb[(size_t)iv.w * DIM + c];

    // diffs (pre-STE, used for loss); STE output = fl(z + diff)
    float dx = e0 - zv.x, dy = e1 - zv.y, dz = e2 - zv.z, dw = e3 - zv.w;
    float4 ov = make_float4(zv.x + dx, zv.y + dy, zv.z + dz, zv.w + dw);
    *(float4*)(out + zoff) = ov;

    float sq = dx * dx + dy * dy + dz * dz + dw * dw;

    #pragma unroll
    for (int m = 32; m >= 1; m >>= 1) sq += __shfl_xor(sq, m, 64);
    __shared__ float red[4];
    if ((t & 63) == 0) red[t >> 6] = sq;
    __syncthreads();
    if (t == 0) partials[bid] = red[0] + red[1] + red[2] + red[3];
}

// ---------------------------------------------------------------------------
// K3: finalize loss + perplexity (single block, f64 accumulation)
// ---------------------------------------------------------------------------
__global__ void k_final(const float* __restrict__ partials,
                        const int* __restrict__ hist,
                        float* __restrict__ out) {
    int t = threadIdx.x;
    double ls = 0.0, es = 0.0;
    for (int i = t; i < 4096; i += 256) ls += (double)partials[i];
    for (int i = t; i < NE; i += 256) {
        double em = (double)hist[i] / (double)NPTS;
        es += em * log(em + 1e-10);
    }
    __shared__ double s1[256], s2[256];
    s1[t] = ls; s2[t] = es;
    __syncthreads();
    for (int s = 128; s > 0; s >>= 1) {
        if (t < s) { s1[t] += s1[t + s]; s2[t] += s2[t + s]; }
        __syncthreads();
    }
    if (t == 0) {
        out[OFF_LOSS] = (float)(s1[0] / (double)ZQ_N * 1.25);  // (1+beta)*mean
        out[OFF_PERP] = (float)exp(-s2[0]);
    }
}

// ---------------------------------------------------------------------------
extern "C" void kernel_launch(void* const* d_in, const int* in_sizes, int n_in,
                              void* d_out, int out_size, void* d_ws, size_t ws_size,
                              hipStream_t stream) {
    const float* z   = (const float*)d_in[0];   // [16,256,32,32] f32
    const float* emb = (const float*)d_in[1];   // [8192,256] f32
    float* out = (float*)d_out;
    char*  ws  = (char*)d_ws;

    // ws layout (bytes), total ~432KB
    float* zsq      = (float*)(ws);                 // 16384 f32
    int*   hist     = (int*)  (ws + 65536);         // 8192 i32
    float* cand_d   = (float*)(ws + 98304);         // 2*16384 f32
    int*   cand_c   = (int*)  (ws + 229376);        // 2*16384 i32
    int*   idx_i    = (int*)  (ws + 360448);        // 16384 i32
    float* partials = (float*)(ws + 425984);        // 4096 f32

    k_zsq   <<<128, 256, 0, stream>>>(z, zsq);
    k_init  <<<32, 256, 0, stream>>>(hist);
    k_argmin<<<256 * SPLITS, 256, 0, stream>>>(z, emb, zsq, cand_d, cand_c);
    k_pick  <<<NPTS / 256, 256, 0, stream>>>(cand_d, cand_c, idx_i, hist, out);
    k_gather<<<BIMG * DIM, 256, 0, stream>>>(z, emb, idx_i, out, partials);
    k_final <<<1, 256, 0, stream>>>(partials, hist, out);
}